// Round 1
// baseline (253.456 us; speedup 1.0000x reference)
//
#include <hip/hip_runtime.h>

#define NT 24
#define SQ 1024
#define NB 1024
#define KC 16
#define NCHUNK (SQ / KC)

__device__ __forceinline__ float fast_exp(float x) { return __expf(x); }
__device__ __forceinline__ float fast_log(float x) { return __logf(x); }

struct CrfState {
    float w;       // working (quasi-normalized) forward prob for this lane's tag
    float logZ;    // accumulated log normalizer (natural log)
    float num;     // numerator accumulator
    int prevTag;
    int lastTag;
};

// Process one chunk of KC steps. t0 is a multiple of KC (so (t0+k)&7 == k&7).
__device__ __forceinline__ void compute_chunk(
    bool first,
    const float (&em)[KC],        // em[k] = feature[b, t0+k, jj] for this lane
    int pkbuf,                    // lane k<16 holds (tag | mask<<8) for step t0+k
    const float (&Ecol)[NT],      // Ecol[i] = exp(trans[i][jj])
    const float* __restrict__ ldsT,
    const float* __restrict__ ldsStart,
    float (*ldsP)[32],            // [2][32] p double-buffer for this group
    int lane, bool act,
    CrfState& st)
{
#pragma unroll
    for (int k = 0; k < KC; ++k) {
        const int rb = (k + 1) & 1;   // read buffer (prev step's write)
        const int wb = k & 1;         // write buffer
        int pkt = __shfl(pkbuf, k, 32);
        int tg = pkt & 31;
        int mk = pkt >> 8;
        if (first && k == 0) {
            // t = 0 init: s0_j = start_j + em0_j ; w = exp(s0), logZ = 0
            float s0 = ldsStart[lane < NT ? lane : NT - 1] + em[0];
            st.w = fast_exp(s0);
            st.num = ldsStart[tg] + __shfl(em[0], tg, 32);
            st.prevTag = tg;
            st.lastTag = tg;
            if (act) ldsP[0][lane] = st.w;
        } else {
            // ---- numerator (off recurrence critical path) ----
            float em_at = __shfl(em[k], tg, 32);            // em[t, tag_t]
            float tr = ldsT[st.prevTag * NT + tg];          // trans[prev, cur]
            // ---- denominator step: w' = (w @ E) * exp(em) ----
            float expem = fast_exp(em[k]);
            const float4* p4 = (const float4*)(&ldsP[rb][0]);
            float4 P0 = p4[0], P1 = p4[1], P2 = p4[2];
            float4 P3 = p4[3], P4v = p4[4], P5 = p4[5];
            float a0 = P0.x * Ecol[0];
            float a1 = P0.y * Ecol[1];
            float a2 = P0.z * Ecol[2];
            float a3 = P0.w * Ecol[3];
            a0 = fmaf(P1.x, Ecol[4], a0);
            a1 = fmaf(P1.y, Ecol[5], a1);
            a2 = fmaf(P1.z, Ecol[6], a2);
            a3 = fmaf(P1.w, Ecol[7], a3);
            a0 = fmaf(P2.x, Ecol[8], a0);
            a1 = fmaf(P2.y, Ecol[9], a1);
            a2 = fmaf(P2.z, Ecol[10], a2);
            a3 = fmaf(P2.w, Ecol[11], a3);
            a0 = fmaf(P3.x, Ecol[12], a0);
            a1 = fmaf(P3.y, Ecol[13], a1);
            a2 = fmaf(P3.z, Ecol[14], a2);
            a3 = fmaf(P3.w, Ecol[15], a3);
            a0 = fmaf(P4v.x, Ecol[16], a0);
            a1 = fmaf(P4v.y, Ecol[17], a1);
            a2 = fmaf(P4v.z, Ecol[18], a2);
            a3 = fmaf(P4v.w, Ecol[19], a3);
            a0 = fmaf(P5.x, Ecol[20], a0);
            a1 = fmaf(P5.y, Ecol[21], a1);
            a2 = fmaf(P5.z, Ecol[22], a2);
            a3 = fmaf(P5.w, Ecol[23], a3);
            float q = (a0 + a1) + (a2 + a3);
            float wn = q * expem;
            bool m = (mk != 0);
            st.w = m ? wn : st.w;                 // where(mask, nxt, score)
            st.num += m ? (tr + em_at) : 0.0f;
            st.lastTag = m ? tg : st.lastTag;
            st.prevTag = tg;
            // renormalize every 8 steps (t0 multiple of 16 -> use k parity)
            if ((k & 7) == 7) {
                float z = act ? st.w : 0.0f;
                z += __shfl_xor(z, 1, 32);
                z += __shfl_xor(z, 2, 32);
                z += __shfl_xor(z, 4, 32);
                z += __shfl_xor(z, 8, 32);
                z += __shfl_xor(z, 16, 32);
                st.logZ += fast_log(z);
                st.w *= __builtin_amdgcn_rcpf(z);
            }
            if (act) ldsP[wb][lane] = st.w;
        }
    }
}

extern "C" __global__ void __launch_bounds__(64)
crf_fwd(const float* __restrict__ feat,   // [B, S, NT] f32
        const int* __restrict__ mask,     // [B, S] i32
        const int* __restrict__ target,   // [B, S] i32
        const float* __restrict__ startT, // [NT]
        const float* __restrict__ endT,   // [NT]
        const float* __restrict__ trans,  // [NT, NT]
        float* __restrict__ llh)          // [B] per-batch log-likelihood
{
    __shared__ float ldsT[NT * NT];
    __shared__ float ldsStart[NT];
    __shared__ float ldsEnd[NT];
    __shared__ __align__(16) float ldsPbuf[2][2][32]; // [group][buf][lane]

    const int tid = threadIdx.x;
    const int g = tid >> 5;
    const int lane = tid & 31;
    const int jj = lane < NT ? lane : NT - 1;
    const bool act = lane < NT;
    const int b = blockIdx.x * 2 + g;

    for (int i = tid; i < NT * NT; i += 64) ldsT[i] = trans[i];
    if (tid < NT) { ldsStart[tid] = startT[tid]; ldsEnd[tid] = endT[tid]; }
    __syncthreads();

    // E column for this lane in registers: Ecol[i] = exp(trans[i][jj])
    float Ecol[NT];
#pragma unroll
    for (int i = 0; i < NT; ++i) Ecol[i] = fast_exp(ldsT[i * NT + jj]);

    const float* fb = feat + (size_t)b * SQ * NT;
    const int* mb = mask + b * SQ;
    const int* tb = target + b * SQ;

    float emA[KC], emB[KC];
    int pkA = 0, pkB = 0;

    // prefetch chunk 0 -> A
#pragma unroll
    for (int k = 0; k < KC; ++k) emA[k] = fb[k * NT + jj];
    {
        int t = lane & (KC - 1);  // lanes 16..31 duplicate lanes 0..15 (harmless)
        pkA = (tb[t] & 31) | (mb[t] ? 256 : 0);
    }

    CrfState st;
    st.w = 0.f; st.logZ = 0.f; st.num = 0.f; st.prevTag = 0; st.lastTag = 0;

#pragma unroll 1
    for (int c2 = 0; c2 < NCHUNK; c2 += 2) {
        { // prefetch chunk c2+1 -> B
            int t0n = (c2 + 1) * KC;
#pragma unroll
            for (int k = 0; k < KC; ++k) emB[k] = fb[(t0n + k) * NT + jj];
            int t = t0n + (lane & (KC - 1));
            pkB = (tb[t] & 31) | (mb[t] ? 256 : 0);
        }
        compute_chunk(c2 == 0, emA, pkA, Ecol, ldsT, ldsStart, ldsPbuf[g], lane, act, st);
        if (c2 + 2 < NCHUNK) { // prefetch chunk c2+2 -> A
            int t0n = (c2 + 2) * KC;
#pragma unroll
            for (int k = 0; k < KC; ++k) emA[k] = fb[(t0n + k) * NT + jj];
            int t = t0n + (lane & (KC - 1));
            pkA = (tb[t] & 31) | (mb[t] ? 256 : 0);
        }
        compute_chunk(false, emB, pkB, Ecol, ldsT, ldsStart, ldsPbuf[g], lane, act, st);
    }

    // epilogue: denominator = logZ + log(sum_j w_j * exp(end_j))
    float zf = act ? st.w * fast_exp(ldsEnd[jj]) : 0.0f;
    zf += __shfl_xor(zf, 1, 32);
    zf += __shfl_xor(zf, 2, 32);
    zf += __shfl_xor(zf, 4, 32);
    zf += __shfl_xor(zf, 8, 32);
    zf += __shfl_xor(zf, 16, 32);
    float denom = st.logZ + fast_log(zf);
    float numer = st.num + ldsEnd[st.lastTag];
    if (lane == 0) llh[b] = numer - denom;
}

extern "C" __global__ void __launch_bounds__(256)
crf_reduce(const float* __restrict__ llh, float* __restrict__ out)
{
    __shared__ float part[4];
    float s = 0.f;
    for (int i = threadIdx.x; i < NB; i += 256) s += llh[i];
#pragma unroll
    for (int m = 1; m < 64; m <<= 1) s += __shfl_xor(s, m, 64);
    if ((threadIdx.x & 63) == 0) part[threadIdx.x >> 6] = s;
    __syncthreads();
    if (threadIdx.x == 0)
        out[0] = -(part[0] + part[1] + part[2] + part[3]) * (1.0f / NB);
}

extern "C" void kernel_launch(void* const* d_in, const int* in_sizes, int n_in,
                              void* d_out, int out_size, void* d_ws, size_t ws_size,
                              hipStream_t stream)
{
    const float* feat   = (const float*)d_in[0];
    const int*   maskp  = (const int*)d_in[1];
    const int*   target = (const int*)d_in[2];
    const float* startT = (const float*)d_in[3];
    const float* endT   = (const float*)d_in[4];
    const float* trans  = (const float*)d_in[5];
    float* llh = (float*)d_ws;   // NB floats of scratch

    crf_fwd<<<NB / 2, 64, 0, stream>>>(feat, maskp, target, startT, endT, trans, llh);
    crf_reduce<<<1, 256, 0, stream>>>(llh, (float*)d_out);
}

// Round 2
// 178.512 us; speedup vs baseline: 1.4198x; 1.4198x over previous
//
#include <hip/hip_runtime.h>

#define NT 24
#define SQ 1024
#define NB 1024
#define KC 16
#define NCH (SQ / KC)

// ---------------------------------------------------------------------------
// w-recurrence over one 16-step chunk.
// Per step: read 24 prev-w from LDS (6 x b128, uniform-address broadcast),
// 24-FMA tree, scale by exp(em), mask-select, every-4-steps renormalize by
// rcp(sum of the just-loaded P values) -- no cross-lane ops anywhere.
// Invariant: true_logscore_j = lz2*ln2 + ln(w_j).
// ---------------------------------------------------------------------------
template <bool FIRST>
__device__ __forceinline__ void run_chunk(
    const float (&em)[KC], unsigned mbits,
    const float (&Ecol)[NT],
    float (*ldsP)[32],          // [2][32] double buffer for this group
    const float* __restrict__ ldsStart,
    int lane, int jj,
    float& w, float& lz2)
{
#pragma unroll
    for (int k = 0; k < KC; ++k) {
        if (FIRST && k == 0) {
            // t = 0: w_j = exp(start_j + em0_j), logZ = 0
            w = __expf(ldsStart[jj] + em[0]);
            ldsP[0][lane] = w;
            continue;
        }
        const int rb = (k + 1) & 1;
        const int wb = k & 1;
        float expem = __expf(em[k]);                  // off critical path
        const float4* p4 = (const float4*)(&ldsP[rb][0]);
        float4 P0 = p4[0], P1 = p4[1], P2 = p4[2];
        float4 P3 = p4[3], P4v = p4[4], P5 = p4[5];
        float a0 = P0.x * Ecol[0];
        float a1 = P0.y * Ecol[1];
        float a2 = P0.z * Ecol[2];
        float a3 = P0.w * Ecol[3];
        a0 = fmaf(P1.x, Ecol[4], a0);
        a1 = fmaf(P1.y, Ecol[5], a1);
        a2 = fmaf(P1.z, Ecol[6], a2);
        a3 = fmaf(P1.w, Ecol[7], a3);
        a0 = fmaf(P2.x, Ecol[8], a0);
        a1 = fmaf(P2.y, Ecol[9], a1);
        a2 = fmaf(P2.z, Ecol[10], a2);
        a3 = fmaf(P2.w, Ecol[11], a3);
        a0 = fmaf(P3.x, Ecol[12], a0);
        a1 = fmaf(P3.y, Ecol[13], a1);
        a2 = fmaf(P3.z, Ecol[14], a2);
        a3 = fmaf(P3.w, Ecol[15], a3);
        a0 = fmaf(P4v.x, Ecol[16], a0);
        a1 = fmaf(P4v.y, Ecol[17], a1);
        a2 = fmaf(P4v.z, Ecol[18], a2);
        a3 = fmaf(P4v.w, Ecol[19], a3);
        a0 = fmaf(P5.x, Ecol[20], a0);
        a1 = fmaf(P5.y, Ecol[21], a1);
        a2 = fmaf(P5.z, Ecol[22], a2);
        a3 = fmaf(P5.w, Ecol[23], a3);
        float q = (a0 + a1) + (a2 + a3);
        bool m = (mbits >> k) & 1;
        float wn = q * expem;
        w = m ? wn : w;
        if ((k & 3) == 3) {
            // z = sum of the P values loaded this step (w_{t-1}); all adds,
            // computed in parallel with the FMA tree, off the chain.
            float z0 = (P0.x + P0.y) + (P0.z + P0.w);
            float z1 = (P1.x + P1.y) + (P1.z + P1.w);
            float z2 = (P2.x + P2.y) + (P2.z + P2.w);
            float z3 = (P3.x + P3.y) + (P3.z + P3.w);
            float z4 = (P4v.x + P4v.y) + (P4v.z + P4v.w);
            float z5 = (P5.x + P5.y) + (P5.z + P5.w);
            float z = ((z0 + z1) + (z2 + z3)) + (z4 + z5);
            w *= __builtin_amdgcn_rcpf(z);   // applied to both mask branches:
            lz2 += __log2f(z);               // invariant stays exact
        }
        ldsP[wb][lane] = w;
    }
}

// Numerator for one chunk: lane k (<16) owns step t0+k. All data from LDS
// (packed tag|mask bytes) + one prefetched global gather em[t, tag_t].
template <bool FIRST>
__device__ __forceinline__ void num_chunk(
    int byc, int byp, float gem,
    const float* __restrict__ ldsT, const float* __restrict__ ldsStart,
    int lane, float& numAcc, int& cnt)
{
    if (lane < 16) {
        int m = byc >> 7;
        int cu = byc & 31;
        int pv = byp & 31;
        float contrib;
        if (FIRST && lane == 0)
            contrib = ldsStart[cu] + gem;              // score0 (unmasked)
        else
            contrib = m ? (ldsT[pv * NT + cu] + gem) : 0.0f;
        numAcc += contrib;
        cnt += m;
    }
}

extern "C" __global__ void __launch_bounds__(64)
crf_fwd(const float* __restrict__ feat,   // [B, S, NT] f32
        const int* __restrict__ maskp,    // [B, S] i32
        const int* __restrict__ target,   // [B, S] i32
        const float* __restrict__ startT, // [NT]
        const float* __restrict__ endT,   // [NT]
        const float* __restrict__ trans,  // [NT, NT]
        float* __restrict__ llh)          // [B]
{
    __shared__ float ldsT[NT * NT];
    __shared__ float ldsStart[NT];
    __shared__ float ldsEnd[NT];
    __shared__ unsigned char ldsTag[2 * SQ];           // tag|mask<<7, per batch
    __shared__ __align__(16) float ldsPbuf[2][2][32];  // [group][buf][lane]

    const int tid = threadIdx.x;
    const int g = tid >> 5;
    const int lane = tid & 31;
    const int jj = lane < NT ? lane : NT - 1;
    const int b0 = blockIdx.x * 2;

    for (int i = tid; i < NT * NT; i += 64) ldsT[i] = trans[i];
    if (tid < NT) { ldsStart[tid] = startT[tid]; ldsEnd[tid] = endT[tid]; }
    for (int i = tid; i < 2 * SQ; i += 64) {
        int tg = target[(size_t)b0 * SQ + i];
        int mk = maskp[(size_t)b0 * SQ + i];
        ldsTag[i] = (unsigned char)((tg & 31) | (mk ? 128 : 0));
    }
    __syncthreads();

    float Ecol[NT];
#pragma unroll
    for (int i = 0; i < NT; ++i) Ecol[i] = __expf(ldsT[i * NT + jj]);

    const float* fb = feat + (size_t)(b0 + g) * SQ * NT;
    const unsigned char* tags = ldsTag + g * SQ;
    float (*ldsP)[32] = ldsPbuf[g];
    const int lk = lane & 15;

    float emA[KC], emB[KC];
    int bycA, bypA, bycB, bypB;
    float gA, gB;
    unsigned mbitsA, mbitsB;

    // prefetch chunk 0 -> A
#pragma unroll
    for (int k = 0; k < KC; ++k) emA[k] = fb[k * NT + jj];
    bycA = tags[lk];
    bypA = tags[lk > 0 ? lk - 1 : 0];
    gA = fb[lk * NT + (bycA & 31)];
    mbitsA = (unsigned)(__ballot(bycA >> 7) >> (g * 32)) & 0xffffu;

    float w = 0.f, lz2 = 0.f, numAcc = 0.f;
    int cnt = 0;

#pragma unroll 1
    for (int c2 = 0; c2 < NCH; c2 += 2) {
        { // prefetch chunk c2+1 -> B
            int t0 = (c2 + 1) * KC;
#pragma unroll
            for (int k = 0; k < KC; ++k) emB[k] = fb[(t0 + k) * NT + jj];
            bycB = tags[t0 + lk];
            bypB = tags[t0 + lk - 1];
            gB = fb[(t0 + lk) * NT + (bycB & 31)];
            mbitsB = (unsigned)(__ballot(bycB >> 7) >> (g * 32)) & 0xffffu;
        }
        if (c2 == 0) {
            num_chunk<true>(bycA, bypA, gA, ldsT, ldsStart, lane, numAcc, cnt);
            run_chunk<true>(emA, mbitsA, Ecol, ldsP, ldsStart, lane, jj, w, lz2);
        } else {
            num_chunk<false>(bycA, bypA, gA, ldsT, ldsStart, lane, numAcc, cnt);
            run_chunk<false>(emA, mbitsA, Ecol, ldsP, ldsStart, lane, jj, w, lz2);
        }
        if (c2 + 2 < NCH) { // prefetch chunk c2+2 -> A
            int t0 = (c2 + 2) * KC;
#pragma unroll
            for (int k = 0; k < KC; ++k) emA[k] = fb[(t0 + k) * NT + jj];
            bycA = tags[t0 + lk];
            bypA = tags[t0 + lk - 1];
            gA = fb[(t0 + lk) * NT + (bycA & 31)];
            mbitsA = (unsigned)(__ballot(bycA >> 7) >> (g * 32)) & 0xffffu;
        }
        num_chunk<false>(bycB, bypB, gB, ldsT, ldsStart, lane, numAcc, cnt);
        run_chunk<false>(emB, mbitsB, Ecol, ldsP, ldsStart, lane, jj, w, lz2);
    }

    // epilogue: denominator = lz2*ln2 + log(sum_j w_j * exp(end_j))
    float zf = (lane < NT) ? w * __expf(ldsEnd[jj]) : 0.0f;
    zf += __shfl_xor(zf, 1, 32);
    zf += __shfl_xor(zf, 2, 32);
    zf += __shfl_xor(zf, 4, 32);
    zf += __shfl_xor(zf, 8, 32);
    zf += __shfl_xor(zf, 16, 32);
    float denom = lz2 * 0.6931471805599453f + __logf(zf);

    float ns = numAcc;
    ns += __shfl_xor(ns, 1, 32);
    ns += __shfl_xor(ns, 2, 32);
    ns += __shfl_xor(ns, 4, 32);
    ns += __shfl_xor(ns, 8, 32);
    ns += __shfl_xor(ns, 16, 32);
    int cs = cnt;
    cs += __shfl_xor(cs, 1, 32);
    cs += __shfl_xor(cs, 2, 32);
    cs += __shfl_xor(cs, 4, 32);
    cs += __shfl_xor(cs, 8, 32);
    cs += __shfl_xor(cs, 16, 32);

    if (lane == 0) {
        int lastTag = tags[cs - 1] & 31;
        llh[b0 + g] = (ns + ldsEnd[lastTag]) - denom;
    }
}

extern "C" __global__ void __launch_bounds__(256)
crf_reduce(const float* __restrict__ llh, float* __restrict__ out)
{
    __shared__ float part[4];
    float s = 0.f;
    for (int i = threadIdx.x; i < NB; i += 256) s += llh[i];
#pragma unroll
    for (int m = 1; m < 64; m <<= 1) s += __shfl_xor(s, m, 64);
    if ((threadIdx.x & 63) == 0) part[threadIdx.x >> 6] = s;
    __syncthreads();
    if (threadIdx.x == 0)
        out[0] = -(part[0] + part[1] + part[2] + part[3]) * (1.0f / NB);
}

extern "C" void kernel_launch(void* const* d_in, const int* in_sizes, int n_in,
                              void* d_out, int out_size, void* d_ws, size_t ws_size,
                              hipStream_t stream)
{
    const float* feat   = (const float*)d_in[0];
    const int*   maskp  = (const int*)d_in[1];
    const int*   target = (const int*)d_in[2];
    const float* startT = (const float*)d_in[3];
    const float* endT   = (const float*)d_in[4];
    const float* trans  = (const float*)d_in[5];
    float* llh = (float*)d_ws;

    crf_fwd<<<NB / 2, 64, 0, stream>>>(feat, maskp, target, startT, endT, trans, llh);
    crf_reduce<<<1, 256, 0, stream>>>(llh, (float*)d_out);
}

// Round 3
// 84.860 us; speedup vs baseline: 2.9868x; 2.1036x over previous
//
#include <hip/hip_runtime.h>

#define NT 24
#define SQ 1024
#define NB 1024
#define KC 16
#define LSEG 128
#define WUP 16
#define NSEG (SQ / LSEG)   // 8 segments per batch
#define NMC (LSEG / KC)    // 8 main chunks per segment

// Prefetch bundle for one 16-step chunk.
struct Pref {
    float em[KC];     // em[k] = feature[b, t0+k, jj] for this lane
    int byc;          // tag|mask<<7 at t0+lk (lanes 0..15 own steps)
    int byp;          // tag at t0+lk-1
    float gem;        // feature[b, t0+lk, tag_{t0+lk}]
    unsigned mbits;   // mask bits for the 16 steps
};

template <bool TAGS>
__device__ __forceinline__ void pf_load(
    Pref& pf, const float* __restrict__ fb,
    const int* __restrict__ tb, const int* __restrict__ mb,
    int t0, int jj, int lk, int g32)
{
#pragma unroll
    for (int k = 0; k < KC; ++k) pf.em[k] = fb[(t0 + k) * NT + jj];
    int t = t0 + lk;
    int mk = mb[t];
    if (TAGS) {
        int tg = tb[t] & 31;
        int tp = tb[t > 0 ? t - 1 : 0] & 31;
        pf.byc = tg | (mk ? 128 : 0);
        pf.byp = tp;
        pf.gem = fb[t * NT + tg];
    } else {
        pf.byc = mk ? 128 : 0;
    }
    unsigned long long bal = __ballot(mk != 0);
    pf.mbits = (unsigned)(bal >> (g32 * 32)) & 0xffffu;
}

// MODE: 0 = normal main chunk, 1 = first chunk of sequence (t=0 init),
//       2 = first main chunk after warmup (capture sub2), 3 = warmup.
// Invariant maintained: true_logscore_j = lz2*ln2 + ln(w_j).
template <int MODE>
__device__ __forceinline__ void run_chunk(
    const Pref& pf, const float (&Ecol)[NT],
    float (*ldsP)[32], const float* __restrict__ ldsT,
    const float* __restrict__ ldsStart,
    int lane, int jj,
    float& w, float& lz2, float& sub2, float& numAcc)
{
    // ---- numerator: lane k<16 owns step t0+k (off the w critical path) ----
    if (MODE != 3 && lane < 16) {
        int m = pf.byc >> 7;
        int cu = pf.byc & 31;
        float contrib;
        if (MODE == 1 && lane == 0)
            contrib = ldsStart[cu] + pf.gem;                 // score0, unmasked
        else
            contrib = m ? (ldsT[pf.byp * NT + cu] + pf.gem) : 0.0f;
        numAcc += contrib;
    }
    // ---- w recurrence ----
#pragma unroll
    for (int k = 0; k < KC; ++k) {
        if (MODE == 1 && k == 0) {
            w = __expf(ldsStart[jj] + pf.em[0]);
            ldsP[0][lane] = w;
            continue;
        }
        const int rb = (k + 1) & 1;
        const int wb = k & 1;
        float expem = __expf(pf.em[k]);
        const float4* p4 = (const float4*)(&ldsP[rb][0]);
        float4 P0 = p4[0], P1 = p4[1], P2 = p4[2];
        float4 P3 = p4[3], P4v = p4[4], P5 = p4[5];
        float a0 = P0.x * Ecol[0];
        float a1 = P0.y * Ecol[1];
        float a2 = P0.z * Ecol[2];
        float a3 = P0.w * Ecol[3];
        a0 = fmaf(P1.x, Ecol[4], a0);
        a1 = fmaf(P1.y, Ecol[5], a1);
        a2 = fmaf(P1.z, Ecol[6], a2);
        a3 = fmaf(P1.w, Ecol[7], a3);
        a0 = fmaf(P2.x, Ecol[8], a0);
        a1 = fmaf(P2.y, Ecol[9], a1);
        a2 = fmaf(P2.z, Ecol[10], a2);
        a3 = fmaf(P2.w, Ecol[11], a3);
        a0 = fmaf(P3.x, Ecol[12], a0);
        a1 = fmaf(P3.y, Ecol[13], a1);
        a2 = fmaf(P3.z, Ecol[14], a2);
        a3 = fmaf(P3.w, Ecol[15], a3);
        a0 = fmaf(P4v.x, Ecol[16], a0);
        a1 = fmaf(P4v.y, Ecol[17], a1);
        a2 = fmaf(P4v.z, Ecol[18], a2);
        a3 = fmaf(P4v.w, Ecol[19], a3);
        a0 = fmaf(P5.x, Ecol[20], a0);
        a1 = fmaf(P5.y, Ecol[21], a1);
        a2 = fmaf(P5.z, Ecol[22], a2);
        a3 = fmaf(P5.w, Ecol[23], a3);
        float q = (a0 + a1) + (a2 + a3);
        // sum of the just-loaded P values (w_{t-1}); plain adds, off the chain
        float zfull = 0.0f;
        if (((k & 3) == 3) || (MODE == 2 && k == 0)) {
            float z0 = (P0.x + P0.y) + (P0.z + P0.w);
            float z1 = (P1.x + P1.y) + (P1.z + P1.w);
            float z2 = (P2.x + P2.y) + (P2.z + P2.w);
            float z3 = (P3.x + P3.y) + (P3.z + P3.w);
            float z4 = (P4v.x + P4v.y) + (P4v.z + P4v.w);
            float z5 = (P5.x + P5.y) + (P5.z + P5.w);
            zfull = ((z0 + z1) + (z2 + z3)) + (z4 + z5);
        }
        if (MODE == 2 && k == 0) {
            // state at segment start (= warmup end): cancel arbitrary init scale
            sub2 = lz2 + __log2f(zfull);
        }
        bool m = (pf.mbits >> k) & 1;
        float wn = q * expem;
        w = m ? wn : w;
        if ((k & 3) == 3) {
            w *= __builtin_amdgcn_rcpf(zfull);  // both branches: invariant exact
            lz2 += __log2f(zfull);
        }
        ldsP[wb][lane] = w;
    }
}

extern "C" __global__ void __launch_bounds__(256, 4)
crf_fwd(const float* __restrict__ feat,   // [B, S, NT] f32
        const int* __restrict__ maskp,    // [B, S] i32
        const int* __restrict__ target,   // [B, S] i32
        const float* __restrict__ startT, // [NT]
        const float* __restrict__ endT,   // [NT]
        const float* __restrict__ trans,  // [NT, NT]
        float* __restrict__ dP,           // [NSEG, NB] denom partials
        float* __restrict__ nP,           // [NSEG, NB] numer partials
        int* __restrict__ cP)             // [NSEG, NB] mask-count partials
{
    __shared__ float ldsT[NT * NT];
    __shared__ float ldsStart[NT];
    __shared__ float ldsEnd[NT];
    __shared__ __align__(16) float ldsPbuf[8][2][32];

    const int tid = threadIdx.x;
    const int g = tid >> 5;
    const int lane = tid & 31;
    const int g32 = g & 1;
    const int jj = lane < NT ? lane : NT - 1;
    const int lk = lane & 15;
    const int grp = blockIdx.x * 8 + g;
    const int b = grp >> 3;          // NSEG = 8
    const int p = grp & (NSEG - 1);

    for (int i = tid; i < NT * NT; i += 256) ldsT[i] = trans[i];
    if (tid < NT) { ldsStart[tid] = startT[tid]; ldsEnd[tid] = endT[tid]; }
    __syncthreads();

    float Ecol[NT];
#pragma unroll
    for (int i = 0; i < NT; ++i) Ecol[i] = __expf(ldsT[i * NT + jj]);

    const float* fb = feat + (size_t)b * SQ * NT;
    const int* tb = target + b * SQ;
    const int* mb = maskp + b * SQ;
    float (*ldsP)[32] = ldsPbuf[g];

    float w = 1.0f, lz2 = 0.0f, sub2 = 0.0f, numAcc = 0.0f;
    int cnt = 0;
    const int a = p * LSEG;

    Pref pfA, pfB;
    if (p > 0) {
        // warmup: 16 steps from uniform w at t = a-WUP (projective contraction
        // ~0.1/step => direction exact to f32 by t = a)
        Pref pfW;
        pf_load<false>(pfW, fb, tb, mb, a - WUP, jj, lk, g32);
        pf_load<true>(pfA, fb, tb, mb, a, jj, lk, g32);
        ldsP[1][lane] = 1.0f;   // seed buffer read by warmup step k=0
        run_chunk<3>(pfW, Ecol, ldsP, ldsT, ldsStart, lane, jj, w, lz2, sub2, numAcc);
    } else {
        pf_load<true>(pfA, fb, tb, mb, 0, jj, lk, g32);
    }

#pragma unroll 1
    for (int c2 = 0; c2 < NMC; c2 += 2) {
        if (c2 + 1 < NMC)
            pf_load<true>(pfB, fb, tb, mb, a + (c2 + 1) * KC, jj, lk, g32);
        if (c2 == 0) {
            if (p == 0)
                run_chunk<1>(pfA, Ecol, ldsP, ldsT, ldsStart, lane, jj, w, lz2, sub2, numAcc);
            else
                run_chunk<2>(pfA, Ecol, ldsP, ldsT, ldsStart, lane, jj, w, lz2, sub2, numAcc);
        } else {
            run_chunk<0>(pfA, Ecol, ldsP, ldsT, ldsStart, lane, jj, w, lz2, sub2, numAcc);
        }
        cnt += __popc(pfA.mbits);
        if (c2 + 2 < NMC)
            pf_load<true>(pfA, fb, tb, mb, a + (c2 + 2) * KC, jj, lk, g32);
        run_chunk<0>(pfB, Ecol, ldsP, ldsT, ldsStart, lane, jj, w, lz2, sub2, numAcc);
        cnt += __popc(pfB.mbits);
    }

    // ---- segment epilogue ----
    // partial denom = sum_{t in segment} log zeta_t   (last segment folds in
    // the end-transition weighting of the final state)
    float zf = (lane < NT) ? ((p == NSEG - 1) ? w * __expf(ldsEnd[jj]) : w) : 0.0f;
    zf += __shfl_xor(zf, 1, 32);
    zf += __shfl_xor(zf, 2, 32);
    zf += __shfl_xor(zf, 4, 32);
    zf += __shfl_xor(zf, 8, 32);
    zf += __shfl_xor(zf, 16, 32);
    float res = (lz2 + __log2f(zf) - sub2) * 0.6931471805599453f;

    float ns = numAcc;
    ns += __shfl_xor(ns, 1, 32);
    ns += __shfl_xor(ns, 2, 32);
    ns += __shfl_xor(ns, 4, 32);
    ns += __shfl_xor(ns, 8, 32);
    ns += __shfl_xor(ns, 16, 32);

    if (lane == 0) {
        dP[p * NB + b] = res;
        nP[p * NB + b] = ns;
        cP[p * NB + b] = cnt;
    }
}

extern "C" __global__ void __launch_bounds__(1024)
crf_combine(const float* __restrict__ dP, const float* __restrict__ nP,
            const int* __restrict__ cP, const int* __restrict__ target,
            const float* __restrict__ endT, float* __restrict__ out)
{
    __shared__ float acc[16];
    const int b = threadIdx.x;
    float den = 0.f, num = 0.f;
    int cnt = 0;
#pragma unroll
    for (int p = 0; p < NSEG; ++p) {
        den += dP[p * NB + b];
        num += nP[p * NB + b];
        cnt += cP[p * NB + b];
    }
    int lastTag = target[(size_t)b * SQ + (cnt - 1)] & 31;
    float llh = (num + endT[lastTag]) - den;

    float s = llh;
#pragma unroll
    for (int m = 1; m < 64; m <<= 1) s += __shfl_xor(s, m, 64);
    if ((b & 63) == 0) acc[b >> 6] = s;
    __syncthreads();
    if (b == 0) {
        float t = 0.f;
#pragma unroll
        for (int i = 0; i < 16; ++i) t += acc[i];
        out[0] = -t * (1.0f / NB);
    }
}

extern "C" void kernel_launch(void* const* d_in, const int* in_sizes, int n_in,
                              void* d_out, int out_size, void* d_ws, size_t ws_size,
                              hipStream_t stream)
{
    const float* feat   = (const float*)d_in[0];
    const int*   maskp  = (const int*)d_in[1];
    const int*   target = (const int*)d_in[2];
    const float* startT = (const float*)d_in[3];
    const float* endT   = (const float*)d_in[4];
    const float* trans  = (const float*)d_in[5];

    float* dP = (float*)d_ws;                    // [NSEG*NB]
    float* nP = dP + NSEG * NB;                  // [NSEG*NB]
    int*   cP = (int*)(nP + NSEG * NB);          // [NSEG*NB]

    crf_fwd<<<NB, 256, 0, stream>>>(feat, maskp, target, startT, endT, trans,
                                    dP, nP, cP);
    crf_combine<<<1, 1024, 0, stream>>>(dP, nP, cP, target, endT, (float*)d_out);
}

// Round 5
// 43.308 us; speedup vs baseline: 5.8524x; 1.9595x over previous
//
#include <hip/hip_runtime.h>

#define NT 24
#define SQ 1024
#define NB 1024
#define NSEG 32
#define LSEG 32
#define WUP 16
#define CH 4
#define NMC (LSEG / CH)   // 8 main chunks per segment

typedef float f32x16 __attribute__((ext_vector_type(16)));
typedef short bf16x8 __attribute__((ext_vector_type(8)));
typedef unsigned int uint2v __attribute__((ext_vector_type(2)));

__device__ __forceinline__ unsigned short bfrnd(float x) {
    unsigned u = __float_as_uint(x);
    return (unsigned short)((u + 0x7fffu + ((u >> 16) & 1u)) >> 16);
}
__device__ __forceinline__ unsigned cvtpk(float lo, float hi) {
    unsigned r;
    asm("v_cvt_pk_bf16_f32 %0, %1, %2" : "=v"(r) : "v"(lo), "v"(hi));
    return r;
}

// Per-chunk prefetch bundle (all static-indexed -> registers).
struct Pref {
    float em[CH][12];   // em[k][r]: row R(r)=(r&3)+8*(r>>2)+4*hi of batch c
    int4 msk;           // mask[c][t0..t0+3]
    int tg[2], tgp[2];  // numerator tags, items i=0,1 at t=t0+2*hi+i
    float gem[2];       // feature[b][t][tag_t]
};

template<bool TAGS>
__device__ __forceinline__ void pf_load(
    Pref& pf, const float* __restrict__ fbl, const int* __restrict__ tbl,
    const int* __restrict__ mbl, int t0, int hi)
{
#pragma unroll
    for (int k = 0; k < CH; ++k) {
        const float* r = fbl + (size_t)(t0 + k) * NT + hi * 4;
        float4 e0 = *(const float4*)(r);
        float4 e1 = *(const float4*)(r + 8);
        float4 e2 = *(const float4*)(r + 16);
        pf.em[k][0] = e0.x; pf.em[k][1] = e0.y; pf.em[k][2] = e0.z; pf.em[k][3] = e0.w;
        pf.em[k][4] = e1.x; pf.em[k][5] = e1.y; pf.em[k][6] = e1.z; pf.em[k][7] = e1.w;
        pf.em[k][8] = e2.x; pf.em[k][9] = e2.y; pf.em[k][10] = e2.z; pf.em[k][11] = e2.w;
    }
    pf.msk = *(const int4*)(mbl + t0);
    if (TAGS) {
#pragma unroll
        for (int i = 0; i < 2; ++i) {
            int t = t0 + 2 * hi + i;
            pf.tg[i] = tbl[t];
            pf.tgp[i] = tbl[t > 0 ? t - 1 : 0];
            pf.gem[i] = fbl[(size_t)t * NT + pf.tg[i]];
        }
    }
}

// MODE: 0 normal, 1 first chunk of sequence (t=0 init), 3 warmup (no numerator)
template<int MODE>
__device__ __forceinline__ void run_chunk(
    const Pref& pf, bf16x8 A1, bf16x8 A2,
    const float* __restrict__ ldsT, const float* __restrict__ ldsS,
    int hi, float (&w)[12], float& lz2, float& numAcc, int& cnt)
{
    // ---- numerator: 4 steps x 32 batches, 2 items per lane (off w-chain) ----
    if (MODE != 3) {
#pragma unroll
        for (int i = 0; i < 2; ++i) {
            int mlo = (i == 0) ? pf.msk.x : pf.msk.y;
            int mhi = (i == 0) ? pf.msk.z : pf.msk.w;
            int m = hi ? mhi : mlo;
            float contrib;
            if (MODE == 1 && hi == 0 && i == 0)
                contrib = ldsS[pf.tg[0]] + pf.gem[0];   // t=0: start+em0, unmasked
            else
                contrib = m ? (ldsT[pf.tgp[i] * NT + pf.tg[i]] + pf.gem[i]) : 0.0f;
            numAcc += contrib;
        }
        if (hi == 0)
            cnt += (pf.msk.x ? 1 : 0) + (pf.msk.y ? 1 : 0) +
                   (pf.msk.z ? 1 : 0) + (pf.msk.w ? 1 : 0);
    }
    // ---- w recurrence: 4 steps, all in registers ----
#pragma unroll
    for (int k = 0; k < CH; ++k) {
        int mkk = (k == 0) ? pf.msk.x : (k == 1) ? pf.msk.y : (k == 2) ? pf.msk.z : pf.msk.w;
        if (MODE == 1 && k == 0) {
#pragma unroll
            for (int r = 0; r < 12; ++r) {
                int R = (r & 3) + 8 * (r >> 2);
                w[r] = __expf(ldsS[R + 4 * hi] + pf.em[0][r]);
            }
            continue;
        }
        // B = bf16(W) in MFMA-B layout via cvt_pk + permlane32_swap.
        // Semantics f(x,y)->(x',y'): x' = {x_lo, y_lo(partner)}, y' = {x_hi(partner), y_hi}.
        // hi=0 lane needs u[0..3] = rows(0..7) = {aw,bw local; aw,bw from hi=1 partner}
        // hi=1 lane needs u[0..3] = rows(8..15) = {cw,dw from hi=0 partner; cw,dw local}
        unsigned aw = cvtpk(w[0], w[1]);
        unsigned bw = cvtpk(w[2], w[3]);
        unsigned cw = cvtpk(w[4], w[5]);
        unsigned dw = cvtpk(w[6], w[7]);
        unsigned ew = cvtpk(w[8], w[9]);
        unsigned fw = cvtpk(w[10], w[11]);
        uint2v s1 = __builtin_amdgcn_permlane32_swap(aw, cw, false, false);
        uint2v s2 = __builtin_amdgcn_permlane32_swap(bw, dw, false, false);
        uint2v s3 = __builtin_amdgcn_permlane32_swap(ew, 0u, false, false);
        uint2v s4 = __builtin_amdgcn_permlane32_swap(fw, 0u, false, false);
        union { unsigned u[4]; bf16x8 v; } B1, B2;
        B1.u[0] = s1[0]; B1.u[1] = s2[0]; B1.u[2] = s1[1]; B1.u[3] = s2[1];
        B2.u[0] = s3[0]; B2.u[1] = s4[0]; B2.u[2] = s3[1]; B2.u[3] = s4[1];
        f32x16 acc = {};
        acc = __builtin_amdgcn_mfma_f32_32x32x16_bf16(A1, B1.v, acc, 0, 0, 0);
        acc = __builtin_amdgcn_mfma_f32_32x32x16_bf16(A2, B2.v, acc, 0, 0, 0);
        bool m = (mkk != 0);
#pragma unroll
        for (int r = 0; r < 12; ++r) {
            float q = acc[r] * __expf(pf.em[k][r]);
            w[r] = m ? q : w[r];
        }
        if (k == CH - 1) {  // renormalize once per chunk (invariant exact)
            float zh = ((w[0] + w[1]) + (w[2] + w[3])) +
                       ((w[4] + w[5]) + (w[6] + w[7])) +
                       ((w[8] + w[9]) + (w[10] + w[11]));
            float zt = zh + __shfl_xor(zh, 32);
            float rz = __builtin_amdgcn_rcpf(zt);
            lz2 += __log2f(zt);
#pragma unroll
            for (int r = 0; r < 12; ++r) w[r] *= rz;
        }
    }
}

extern "C" __global__ void __launch_bounds__(64)
crf_fwd(const float* __restrict__ feat,   // [B, S, NT]
        const int* __restrict__ maskp,    // [B, S]
        const int* __restrict__ target,   // [B, S]
        const float* __restrict__ startT, const float* __restrict__ endT,
        const float* __restrict__ trans,  // [NT, NT]
        float* __restrict__ dP, float* __restrict__ nP, int* __restrict__ cP)
{
    __shared__ float ldsT[NT * NT];
    __shared__ float ldsS[NT];
    __shared__ float ldsE[NT];

    const int tid = threadIdx.x;
    const int hi = tid >> 5;
    const int c = tid & 31;
    const int grp = blockIdx.x;          // 1024 groups = (bg, p)
    const int bg = grp >> 5;             // NSEG = 32
    const int p = grp & (NSEG - 1);
    const int b = bg * 32 + c;

    for (int i = tid; i < NT * NT; i += 64) ldsT[i] = trans[i];
    if (tid < NT) { ldsS[tid] = startT[tid]; ldsE[tid] = endT[tid]; }
    __syncthreads();

    // A = exp(trans^T) constant frags: A[row=c][k] = exp(trans[k][c]), pad 0
    union { unsigned short s[8]; bf16x8 v; } A1u, A2u;
#pragma unroll
    for (int j = 0; j < 8; ++j) {
        int k1 = 8 * hi + j;
        float v1 = (c < NT && k1 < NT) ? __expf(ldsT[k1 * NT + c]) : 0.0f;
        A1u.s[j] = bfrnd(v1);
        int k2 = 16 + 8 * hi + j;
        float v2 = (c < NT && k2 < NT) ? __expf(ldsT[k2 * NT + c]) : 0.0f;
        A2u.s[j] = bfrnd(v2);
    }

    const float* fbl = feat + (size_t)b * SQ * NT;
    const int* tbl = target + (size_t)b * SQ;
    const int* mbl = maskp + (size_t)b * SQ;

    float w[12];
    float lz2 = 0.0f, sub2 = 0.0f, numAcc = 0.0f;
    int cnt = 0;
    const int a = p * LSEG;
    Pref pfA, pfB;

    if (p > 0) {
#pragma unroll
        for (int r = 0; r < 12; ++r) w[r] = 1.0f;   // uniform seed
        pf_load<false>(pfA, fbl, tbl, mbl, a - 16, hi);
        pf_load<false>(pfB, fbl, tbl, mbl, a - 12, hi);
        run_chunk<3>(pfA, A1u.v, A2u.v, ldsT, ldsS, hi, w, lz2, numAcc, cnt);
        pf_load<false>(pfA, fbl, tbl, mbl, a - 8, hi);
        run_chunk<3>(pfB, A1u.v, A2u.v, ldsT, ldsS, hi, w, lz2, numAcc, cnt);
        pf_load<false>(pfB, fbl, tbl, mbl, a - 4, hi);
        run_chunk<3>(pfA, A1u.v, A2u.v, ldsT, ldsS, hi, w, lz2, numAcc, cnt);
        pf_load<true>(pfA, fbl, tbl, mbl, a, hi);
        run_chunk<3>(pfB, A1u.v, A2u.v, ldsT, ldsS, hi, w, lz2, numAcc, cnt);
        pf_load<true>(pfB, fbl, tbl, mbl, a + 4, hi);
        // capture segment-start scale (state = w_{a-1}): cancels warmup init
        float zh = ((w[0] + w[1]) + (w[2] + w[3])) + ((w[4] + w[5]) + (w[6] + w[7])) +
                   ((w[8] + w[9]) + (w[10] + w[11]));
        float zt = zh + __shfl_xor(zh, 32);
        sub2 = lz2 + __log2f(zt);
#pragma unroll 1
        for (int ch = 0; ch < NMC; ch += 2) {
            run_chunk<0>(pfA, A1u.v, A2u.v, ldsT, ldsS, hi, w, lz2, numAcc, cnt);
            if (ch + 2 < NMC) pf_load<true>(pfA, fbl, tbl, mbl, a + (ch + 2) * 4, hi);
            run_chunk<0>(pfB, A1u.v, A2u.v, ldsT, ldsS, hi, w, lz2, numAcc, cnt);
            if (ch + 3 < NMC) pf_load<true>(pfB, fbl, tbl, mbl, a + (ch + 3) * 4, hi);
        }
    } else {
        pf_load<true>(pfA, fbl, tbl, mbl, 0, hi);
        pf_load<true>(pfB, fbl, tbl, mbl, 4, hi);
        run_chunk<1>(pfA, A1u.v, A2u.v, ldsT, ldsS, hi, w, lz2, numAcc, cnt);
        pf_load<true>(pfA, fbl, tbl, mbl, 8, hi);
        run_chunk<0>(pfB, A1u.v, A2u.v, ldsT, ldsS, hi, w, lz2, numAcc, cnt);
        pf_load<true>(pfB, fbl, tbl, mbl, 12, hi);
#pragma unroll 1
        for (int ch = 2; ch < NMC; ch += 2) {
            run_chunk<0>(pfA, A1u.v, A2u.v, ldsT, ldsS, hi, w, lz2, numAcc, cnt);
            if (ch + 2 < NMC) pf_load<true>(pfA, fbl, tbl, mbl, (ch + 2) * 4, hi);
            run_chunk<0>(pfB, A1u.v, A2u.v, ldsT, ldsS, hi, w, lz2, numAcc, cnt);
            if (ch + 3 < NMC) pf_load<true>(pfB, fbl, tbl, mbl, (ch + 3) * 4, hi);
        }
    }

    // ---- segment epilogue ----
    float ze = 0.0f;
#pragma unroll
    for (int r = 0; r < 12; ++r) {
        int R = (r & 3) + 8 * (r >> 2) + 4 * hi;
        float wv = w[r];
        if (p == NSEG - 1) wv *= __expf(ldsE[R]);
        ze += wv;
    }
    float zt = ze + __shfl_xor(ze, 32);
    float res = (lz2 + __log2f(zt) - sub2) * 0.6931471805599453f;
    float ntot = numAcc + __shfl_xor(numAcc, 32);
    if (hi == 0) {
        dP[p * NB + b] = res;
        nP[p * NB + b] = ntot;
        cP[p * NB + b] = cnt;
    }
}

extern "C" __global__ void __launch_bounds__(64)
crf_combine(const float* __restrict__ dP, const float* __restrict__ nP,
            const int* __restrict__ cP, const int* __restrict__ target,
            const float* __restrict__ endT, float* __restrict__ bpart)
{
    const int b = blockIdx.x * 64 + threadIdx.x;
    float den = 0.f, num = 0.f;
    int cnt = 0;
#pragma unroll
    for (int p = 0; p < NSEG; ++p) {
        den += dP[p * NB + b];
        num += nP[p * NB + b];
        cnt += cP[p * NB + b];
    }
    int lastTag = target[(size_t)b * SQ + (cnt - 1)];
    float llh = (num + endT[lastTag]) - den;
#pragma unroll
    for (int m = 1; m < 64; m <<= 1) llh += __shfl_xor(llh, m, 64);
    if (threadIdx.x == 0) bpart[blockIdx.x] = llh;
}

extern "C" __global__ void __launch_bounds__(64)
crf_final(const float* __restrict__ bpart, float* __restrict__ out)
{
    float s = (threadIdx.x < NB / 64) ? bpart[threadIdx.x] : 0.0f;
#pragma unroll
    for (int m = 1; m < 64; m <<= 1) s += __shfl_xor(s, m, 64);
    if (threadIdx.x == 0) out[0] = -s * (1.0f / NB);
}

extern "C" void kernel_launch(void* const* d_in, const int* in_sizes, int n_in,
                              void* d_out, int out_size, void* d_ws, size_t ws_size,
                              hipStream_t stream)
{
    const float* feat   = (const float*)d_in[0];
    const int*   maskp  = (const int*)d_in[1];
    const int*   target = (const int*)d_in[2];
    const float* startT = (const float*)d_in[3];
    const float* endT   = (const float*)d_in[4];
    const float* trans  = (const float*)d_in[5];

    float* dP = (float*)d_ws;                    // [NSEG*NB]
    float* nP = dP + NSEG * NB;                  // [NSEG*NB]
    int*   cP = (int*)(nP + NSEG * NB);          // [NSEG*NB]
    float* bpart = (float*)(cP + NSEG * NB);     // [NB/64]

    crf_fwd<<<(NB / 32) * NSEG, 64, 0, stream>>>(feat, maskp, target, startT, endT,
                                                 trans, dP, nP, cP);
    crf_combine<<<NB / 64, 64, 0, stream>>>(dP, nP, cP, target, endT, bpart);
    crf_final<<<1, 64, 0, stream>>>(bpart, (float*)d_out);
}